// Round 2
// baseline (2876.836 us; speedup 1.0000x reference)
//
#include <hip/hip_runtime.h>
#include <math.h>

#define N   4096
#define NO  8192
#define TBL_ELEMS (128 * 128 * 32)   // g x r x k

#ifndef M_PI
#define M_PI 3.14159265358979323846
#endif

typedef __attribute__((ext_vector_type(8))) short short8;
typedef __attribute__((ext_vector_type(4))) float f32x4;
typedef __attribute__((ext_vector_type(4))) unsigned short u16x4;

// ws layout: [0,64KB) wf floats (S at wf[N]); [64KB, +2MB) table hi/lo;
// then xh(32MB) xl(32MB) ETh(64MB) ETl(64MB). Total ~194MB; fallback path if ws smaller.

__device__ __forceinline__ unsigned bf16h(float f) {
    unsigned u = __float_as_uint(f);
    return (u + 0x7FFFu + ((u >> 16) & 1u)) >> 16;   // RNE to bf16 bits
}

__global__ void init_weights_kernel(float* w) {
    int m = blockIdx.x * blockDim.x + threadIdx.x;
    if (m < N) {
        double ang = M_PI * (2.0 * (double)m + 1.0) / (2.0 * (double)N);
        double v = (cos(ang) / sin(ang)) / (double)N;
        w[m] = (m & 1) ? (float)(-v) : (float)v;
    }
    if (blockIdx.x == 0 && threadIdx.x == 0) w[N] = 0.0f;
}

// tbl[g][r][k] = wf[(r - k - 32*g) & (N-1)]
__global__ void build_table_kernel(const float* __restrict__ wf,
                                   ushort* __restrict__ th, ushort* __restrict__ tl) {
    int idx = blockIdx.x * 256 + threadIdx.x;
    int k = idx & 31;
    int r = (idx >> 5) & 127;
    int g = idx >> 12;
    int m = (r - k - 32 * g) & (N - 1);
    float f = wf[m];
    unsigned h = bf16h(f);
    float hf = __uint_as_float(h << 16);
    unsigned l = bf16h(f - hf);
    th[idx] = (ushort)h;
    tl[idx] = (ushort)l;
}

__global__ void reduce_sign_kernel(const float* __restrict__ x, float* S) {
    const size_t NN = (size_t)N * N;
    float acc = 0.0f;
    for (size_t idx = (size_t)blockIdx.x * blockDim.x + threadIdx.x; idx < NN;
         idx += (size_t)gridDim.x * blockDim.x) {
        int st = (int)((idx >> 12) + (idx & (N - 1)));
        float v = x[idx];
        acc += (st & 1) ? -v : v;
    }
    #pragma unroll
    for (int off = 32; off > 0; off >>= 1) acc += __shfl_down(acc, off, 64);
    __shared__ float wsum[4];
    int lane = threadIdx.x & 63;
    int wv   = threadIdx.x >> 6;
    if (lane == 0) wsum[wv] = acc;
    __syncthreads();
    if (threadIdx.x == 0) atomicAdd(S, wsum[0] + wsum[1] + wsum[2] + wsum[3]);
}

// x -> xh/xl (row-major bf16 split) + ET even rows (x^T split) + sign-sum S
__global__ __launch_bounds__(256) void convert_x_kernel(const float* __restrict__ x,
        ushort* __restrict__ xh, ushort* __restrict__ xl,
        ushort* __restrict__ ETh, ushort* __restrict__ ETl, float* __restrict__ S) {
    __shared__ uint tile[32][33];
    __shared__ float wsum[4];
    const int bj = blockIdx.x * 32;
    const int bs = blockIdx.y * 32;
    const int tid = threadIdx.x;
    const int row = tid >> 3;         // 0..31
    const int c4  = (tid & 7) << 2;   // 0,4,..,28

    float4 v = *reinterpret_cast<const float4*>(x + (size_t)(bs + row) * N + bj + c4);
    float av[4] = {v.x, v.y, v.z, v.w};
    u16x4 h4, l4;
    float sacc = 0.0f;
    #pragma unroll
    for (int i = 0; i < 4; ++i) {
        unsigned h = bf16h(av[i]);
        float hf = __uint_as_float(h << 16);
        unsigned lo = bf16h(av[i] - hf);
        h4[i] = (unsigned short)h;
        l4[i] = (unsigned short)lo;
        tile[row][c4 + i] = (h << 16) | lo;
        sacc += (((bs + row) + (bj + c4 + i)) & 1) ? -av[i] : av[i];
    }
    size_t ro = (size_t)(bs + row) * N + bj + c4;
    *reinterpret_cast<u16x4*>(xh + ro) = h4;
    *reinterpret_cast<u16x4*>(xl + ro) = l4;

    #pragma unroll
    for (int off = 32; off > 0; off >>= 1) sacc += __shfl_down(sacc, off, 64);
    if ((tid & 63) == 0) wsum[tid >> 6] = sacc;
    __syncthreads();
    if (tid == 0) atomicAdd(S, wsum[0] + wsum[1] + wsum[2] + wsum[3]);

    // transposed write: ET[2*(bj+row)][bs + c4 + i] = x[bs+c4+i][bj+row]
    u16x4 th4, tl4;
    #pragma unroll
    for (int i = 0; i < 4; ++i) {
        uint p = tile[c4 + i][row];
        th4[i] = (unsigned short)(p >> 16);
        tl4[i] = (unsigned short)(p & 0xFFFFu);
    }
    size_t eo = (size_t)(2 * (bj + row)) * N + bs + c4;
    *reinterpret_cast<u16x4*>(ETh + eo) = th4;
    *reinterpret_cast<u16x4*>(ETl + eo) = tl4;
}

// hpass: Z[s][j] = sum_t x[s][t] w[(j-t) mod N]; writes out even rows + ET odd rows.
__global__ __launch_bounds__(256) void hpass_pre(const float* __restrict__ x,
        const ushort* __restrict__ xh, const ushort* __restrict__ xl,
        const ushort* __restrict__ th, const ushort* __restrict__ tl,
        float* __restrict__ out, ushort* __restrict__ ETh, ushort* __restrict__ ETl) {
    const int j0 = blockIdx.x * 128;
    const int s0 = blockIdx.y * 128;
    const int tid = threadIdx.x;
    const int w   = tid >> 6;
    const int l   = tid & 63;
    const int lr  = l & 15;
    const int kb  = (l >> 4) * 8;
    const int wm  = (w >> 1) * 64;
    const int wn  = (w & 1) * 64;

    f32x4 acc[4][4];
    #pragma unroll
    for (int a = 0; a < 4; ++a)
        #pragma unroll
        for (int b = 0; b < 4; ++b)
            acc[a][b] = (f32x4){0.f, 0.f, 0.f, 0.f};

    for (int t0 = 0; t0 < N; t0 += 32) {
        const int g = ((t0 - j0) & (N - 1)) >> 5;
        short8 bh[4], bl[4], ah[4], al[4];
        #pragma unroll
        for (int nf = 0; nf < 4; ++nf) {
            size_t flat = ((size_t)(g * 128 + wn + nf * 16 + lr) << 5) + kb;
            bh[nf] = *reinterpret_cast<const short8*>(th + flat);
            bl[nf] = *reinterpret_cast<const short8*>(tl + flat);
        }
        #pragma unroll
        for (int mf = 0; mf < 4; ++mf) {
            size_t ao = (size_t)(s0 + wm + mf * 16 + lr) * N + t0 + kb;
            ah[mf] = *reinterpret_cast<const short8*>(xh + ao);
            al[mf] = *reinterpret_cast<const short8*>(xl + ao);
        }
        // 3 independent passes: per-acc order is still hh, hl, lh (bitwise same result)
        #pragma unroll
        for (int mf = 0; mf < 4; ++mf)
            #pragma unroll
            for (int nf = 0; nf < 4; ++nf)
                acc[mf][nf] = __builtin_amdgcn_mfma_f32_16x16x32_bf16(ah[mf], bh[nf], acc[mf][nf], 0, 0, 0);
        #pragma unroll
        for (int mf = 0; mf < 4; ++mf)
            #pragma unroll
            for (int nf = 0; nf < 4; ++nf)
                acc[mf][nf] = __builtin_amdgcn_mfma_f32_16x16x32_bf16(ah[mf], bl[nf], acc[mf][nf], 0, 0, 0);
        #pragma unroll
        for (int mf = 0; mf < 4; ++mf)
            #pragma unroll
            for (int nf = 0; nf < 4; ++nf)
                acc[mf][nf] = __builtin_amdgcn_mfma_f32_16x16x32_bf16(al[mf], bh[nf], acc[mf][nf], 0, 0, 0);
    }

    const int crow = (l >> 4) * 4;
    #pragma unroll
    for (int mf = 0; mf < 4; ++mf) {
        const int sbase = s0 + wm + mf * 16 + crow;
        #pragma unroll
        for (int nf = 0; nf < 4; ++nf) {
            const int j = j0 + wn + nf * 16 + lr;
            u16x4 h4, l4;
            #pragma unroll
            for (int i = 0; i < 4; ++i) {
                float zv = acc[mf][nf][i];
                float xv = x[(size_t)(sbase + i) * N + j];
                *reinterpret_cast<float2*>(out + (size_t)(2 * (sbase + i)) * NO + (size_t)(2 * j)) =
                    make_float2(xv, zv);
                unsigned h = bf16h(zv);
                h4[i] = (unsigned short)h;
                l4[i] = (unsigned short)bf16h(zv - __uint_as_float(h << 16));
            }
            size_t eo = (size_t)(2 * j + 1) * N + sbase;
            *reinterpret_cast<u16x4*>(ETh + eo) = h4;
            *reinterpret_cast<u16x4*>(ETl + eo) = l4;
        }
    }
}

// vpass: y[2i+1][b] = sum_s w[(i-s) mod N] * E[s][b] - sign correction (odd b).
__global__ __launch_bounds__(256) void vpass_pre(const ushort* __restrict__ th,
        const ushort* __restrict__ tl, const ushort* __restrict__ ETh,
        const ushort* __restrict__ ETl, const float* __restrict__ S, float* __restrict__ out) {
    const int i0 = blockIdx.x * 128;   // i fastest: blocks sharing ET panel dispatch together
    const int b0 = blockIdx.y * 128;
    const int tid = threadIdx.x;
    const int w   = tid >> 6;
    const int l   = tid & 63;
    const int lr  = l & 15;
    const int kb  = (l >> 4) * 8;
    const int wm  = (w >> 1) * 64;
    const int wn  = (w & 1) * 64;

    f32x4 acc[4][4];
    #pragma unroll
    for (int a = 0; a < 4; ++a)
        #pragma unroll
        for (int b = 0; b < 4; ++b)
            acc[a][b] = (f32x4){0.f, 0.f, 0.f, 0.f};

    for (int s0 = 0; s0 < N; s0 += 32) {
        short8 bh[4], bl[4], ah[4], al[4];
        #pragma unroll
        for (int nf = 0; nf < 4; ++nf) {
            size_t eo = (size_t)(b0 + wn + nf * 16 + lr) * N + s0 + kb;
            bh[nf] = *reinterpret_cast<const short8*>(ETh + eo);
            bl[nf] = *reinterpret_cast<const short8*>(ETl + eo);
        }
        const int g = ((s0 - i0) & (N - 1)) >> 5;
        #pragma unroll
        for (int mf = 0; mf < 4; ++mf) {
            size_t flat = ((size_t)(g * 128 + wm + mf * 16 + lr) << 5) + kb;
            ah[mf] = *reinterpret_cast<const short8*>(th + flat);
            al[mf] = *reinterpret_cast<const short8*>(tl + flat);
        }
        #pragma unroll
        for (int mf = 0; mf < 4; ++mf)
            #pragma unroll
            for (int nf = 0; nf < 4; ++nf)
                acc[mf][nf] = __builtin_amdgcn_mfma_f32_16x16x32_bf16(ah[mf], bh[nf], acc[mf][nf], 0, 0, 0);
        #pragma unroll
        for (int mf = 0; mf < 4; ++mf)
            #pragma unroll
            for (int nf = 0; nf < 4; ++nf)
                acc[mf][nf] = __builtin_amdgcn_mfma_f32_16x16x32_bf16(ah[mf], bl[nf], acc[mf][nf], 0, 0, 0);
        #pragma unroll
        for (int mf = 0; mf < 4; ++mf)
            #pragma unroll
            for (int nf = 0; nf < 4; ++nf)
                acc[mf][nf] = __builtin_amdgcn_mfma_f32_16x16x32_bf16(al[mf], bh[nf], acc[mf][nf], 0, 0, 0);
    }

    const float Sval = S[0] * (1.0f / ((float)N * (float)N));
    const int crow = (l >> 4) * 4;
    #pragma unroll
    for (int mf = 0; mf < 4; ++mf) {
        #pragma unroll
        for (int i = 0; i < 4; ++i) {
            int irow = i0 + wm + mf * 16 + crow + i;
            #pragma unroll
            for (int nf = 0; nf < 4; ++nf) {
                int b = b0 + wn + nf * 16 + lr;
                float v = acc[mf][nf][i];
                if (b & 1) {
                    int jdx = (b - 1) >> 1;
                    v -= (((irow + jdx) & 1) ? -Sval : Sval);
                }
                out[(size_t)(2 * irow + 1) * NO + (size_t)b] = v;
            }
        }
    }
}

// ---------------- fallback (round-1) kernels: used only if workspace is small ----------------
__device__ __forceinline__ void split8(const float4& a0, const float4& a1,
                                       short8& hi, short8& lo) {
    float av[8] = {a0.x, a0.y, a0.z, a0.w, a1.x, a1.y, a1.z, a1.w};
    #pragma unroll
    for (int j = 0; j < 8; ++j) {
        unsigned h = bf16h(av[j]);
        float hf = __uint_as_float(h << 16);
        hi[j] = (short)h;
        lo[j] = (short)bf16h(av[j] - hf);
    }
}

__global__ __launch_bounds__(256) void hpass_fly(const float* __restrict__ x,
        const ushort* __restrict__ th, const ushort* __restrict__ tl,
        float* __restrict__ out) {
    const int j0 = blockIdx.x * 128;
    const int s0 = blockIdx.y * 128;
    const int tid = threadIdx.x;
    const int w = tid >> 6, l = tid & 63;
    const int lr = l & 15, kb = (l >> 4) * 8;
    const int wm = (w >> 1) * 64, wn = (w & 1) * 64;
    f32x4 acc[4][4];
    #pragma unroll
    for (int a = 0; a < 4; ++a)
        #pragma unroll
        for (int b = 0; b < 4; ++b) acc[a][b] = (f32x4){0.f, 0.f, 0.f, 0.f};
    for (int t0 = 0; t0 < N; t0 += 32) {
        const int g = ((t0 - j0) & (N - 1)) >> 5;
        short8 bh[4], bl[4];
        #pragma unroll
        for (int nf = 0; nf < 4; ++nf) {
            size_t flat = ((size_t)(g * 128 + wn + nf * 16 + lr) << 5) + kb;
            bh[nf] = *reinterpret_cast<const short8*>(th + flat);
            bl[nf] = *reinterpret_cast<const short8*>(tl + flat);
        }
        #pragma unroll
        for (int mf = 0; mf < 4; ++mf) {
            const float* ap = x + (size_t)(s0 + wm + mf * 16 + lr) * N + (t0 + kb);
            float4 a0 = *reinterpret_cast<const float4*>(ap);
            float4 a1 = *reinterpret_cast<const float4*>(ap + 4);
            short8 ah, al;
            split8(a0, a1, ah, al);
            #pragma unroll
            for (int nf = 0; nf < 4; ++nf) {
                acc[mf][nf] = __builtin_amdgcn_mfma_f32_16x16x32_bf16(ah, bh[nf], acc[mf][nf], 0, 0, 0);
                acc[mf][nf] = __builtin_amdgcn_mfma_f32_16x16x32_bf16(ah, bl[nf], acc[mf][nf], 0, 0, 0);
                acc[mf][nf] = __builtin_amdgcn_mfma_f32_16x16x32_bf16(al, bh[nf], acc[mf][nf], 0, 0, 0);
            }
        }
    }
    const int crow = (l >> 4) * 4;
    #pragma unroll
    for (int mf = 0; mf < 4; ++mf)
        #pragma unroll
        for (int i = 0; i < 4; ++i) {
            int s = s0 + wm + mf * 16 + crow + i;
            #pragma unroll
            for (int nf = 0; nf < 4; ++nf) {
                int j = j0 + wn + nf * 16 + lr;
                float xv = x[(size_t)s * N + j];
                *reinterpret_cast<float2*>(out + (size_t)(2 * s) * NO + (size_t)(2 * j)) =
                    make_float2(xv, acc[mf][nf][i]);
            }
        }
}

__global__ __launch_bounds__(256) void vpass_fly(const ushort* __restrict__ th,
        const ushort* __restrict__ tl, const float* __restrict__ S, float* out) {
    const int i0 = blockIdx.x * 128;
    const int b0 = blockIdx.y * 128;
    const int tid = threadIdx.x;
    const int w = tid >> 6, l = tid & 63;
    const int lr = l & 15, kb = (l >> 4) * 8;
    const int wm = (w >> 1) * 64, wn = (w & 1) * 64;
    f32x4 acc[4][4];
    #pragma unroll
    for (int a = 0; a < 4; ++a)
        #pragma unroll
        for (int b = 0; b < 4; ++b) acc[a][b] = (f32x4){0.f, 0.f, 0.f, 0.f};
    for (int s0 = 0; s0 < N; s0 += 32) {
        short8 bh[4], bl[4];
        #pragma unroll
        for (int nf = 0; nf < 4; ++nf) {
            int colb = b0 + wn + nf * 16 + lr;
            const float* ep = out + (size_t)(2 * (s0 + kb)) * NO + colb;
            float ev[8];
            #pragma unroll
            for (int j = 0; j < 8; ++j) ev[j] = ep[(size_t)(2 * j) * NO];
            #pragma unroll
            for (int j = 0; j < 8; ++j) {
                unsigned h = bf16h(ev[j]);
                float hf = __uint_as_float(h << 16);
                bh[nf][j] = (short)h;
                bl[nf][j] = (short)bf16h(ev[j] - hf);
            }
        }
        const int g = ((s0 - i0) & (N - 1)) >> 5;
        #pragma unroll
        for (int mf = 0; mf < 4; ++mf) {
            size_t flat = ((size_t)(g * 128 + wm + mf * 16 + lr) << 5) + kb;
            short8 ah = *reinterpret_cast<const short8*>(th + flat);
            short8 al = *reinterpret_cast<const short8*>(tl + flat);
            #pragma unroll
            for (int nf = 0; nf < 4; ++nf) {
                acc[mf][nf] = __builtin_amdgcn_mfma_f32_16x16x32_bf16(ah, bh[nf], acc[mf][nf], 0, 0, 0);
                acc[mf][nf] = __builtin_amdgcn_mfma_f32_16x16x32_bf16(ah, bl[nf], acc[mf][nf], 0, 0, 0);
                acc[mf][nf] = __builtin_amdgcn_mfma_f32_16x16x32_bf16(al, bh[nf], acc[mf][nf], 0, 0, 0);
            }
        }
    }
    const float Sval = S[0] * (1.0f / ((float)N * (float)N));
    const int crow = (l >> 4) * 4;
    #pragma unroll
    for (int mf = 0; mf < 4; ++mf)
        #pragma unroll
        for (int i = 0; i < 4; ++i) {
            int irow = i0 + wm + mf * 16 + crow + i;
            #pragma unroll
            for (int nf = 0; nf < 4; ++nf) {
                int b = b0 + wn + nf * 16 + lr;
                float v = acc[mf][nf][i];
                if (b & 1) {
                    int jdx = (b - 1) >> 1;
                    v -= (((irow + jdx) & 1) ? -Sval : Sval);
                }
                out[(size_t)(2 * irow + 1) * NO + (size_t)b] = v;
            }
        }
}

extern "C" void kernel_launch(void* const* d_in, const int* in_sizes, int n_in,
                              void* d_out, int out_size, void* d_ws, size_t ws_size,
                              hipStream_t stream) {
    const float* x = (const float*)d_in[0];
    float* out = (float*)d_out;
    char* base = (char*)d_ws;
    float* wf = (float*)base;                               // wf[0..N], S at wf[N]
    ushort* th = (ushort*)(base + 65536);
    ushort* tl = th + TBL_ELEMS;

    const size_t need = 65536 + (size_t)4 * TBL_ELEMS
                      + (size_t)4 * N * N            // xh + xl
                      + (size_t)4 * NO * N;          // ETh + ETl
    init_weights_kernel<<<(N + 255) / 256, 256, 0, stream>>>(wf);
    build_table_kernel<<<TBL_ELEMS / 256, 256, 0, stream>>>(wf, th, tl);

    if (ws_size >= need) {
        ushort* xh  = (ushort*)(base + 65536 + (size_t)4 * TBL_ELEMS);
        ushort* xl  = xh + (size_t)N * N;
        ushort* ETh = xl + (size_t)N * N;
        ushort* ETl = ETh + (size_t)NO * N;
        convert_x_kernel<<<dim3(N / 32, N / 32), 256, 0, stream>>>(x, xh, xl, ETh, ETl, wf + N);
        hpass_pre<<<dim3(N / 128, N / 128), 256, 0, stream>>>(x, xh, xl, th, tl, out, ETh, ETl);
        vpass_pre<<<dim3(N / 128, NO / 128), 256, 0, stream>>>(th, tl, ETh, ETl, wf + N, out);
    } else {
        reduce_sign_kernel<<<1024, 256, 0, stream>>>(x, wf + N);
        hpass_fly<<<dim3(N / 128, N / 128), 256, 0, stream>>>(x, th, tl, out);
        vpass_fly<<<dim3(N / 128, NO / 128), 256, 0, stream>>>(th, tl, wf + N, out);
    }
}

// Round 3
// 2783.941 us; speedup vs baseline: 1.0334x; 1.0334x over previous
//
#include <hip/hip_runtime.h>
#include <math.h>

#define N   4096
#define NO  8192
#define TBL_ELEMS (128 * 128 * 32)   // g x r x k

#ifndef M_PI
#define M_PI 3.14159265358979323846
#endif

typedef __attribute__((ext_vector_type(8))) short short8;
typedef __attribute__((ext_vector_type(4))) float f32x4;
typedef __attribute__((ext_vector_type(4))) unsigned short u16x4;

// ws layout: [0,64KB) wf floats (S at wf[N]); [64KB, +2MB) table hi/lo;
// then xh(32MB) xl(32MB) ETh(64MB) ETl(64MB). Total ~194MB; fallback path if ws smaller.

__device__ __forceinline__ unsigned bf16h(float f) {
    unsigned u = __float_as_uint(f);
    return (u + 0x7FFFu + ((u >> 16) & 1u)) >> 16;   // RNE to bf16 bits
}

__global__ void init_weights_kernel(float* w) {
    int m = blockIdx.x * blockDim.x + threadIdx.x;
    if (m < N) {
        double ang = M_PI * (2.0 * (double)m + 1.0) / (2.0 * (double)N);
        double v = (cos(ang) / sin(ang)) / (double)N;
        w[m] = (m & 1) ? (float)(-v) : (float)v;
    }
    if (blockIdx.x == 0 && threadIdx.x == 0) w[N] = 0.0f;
}

// tbl[g][r][k] = wf[(r - k - 32*g) & (N-1)]
__global__ void build_table_kernel(const float* __restrict__ wf,
                                   ushort* __restrict__ th, ushort* __restrict__ tl) {
    int idx = blockIdx.x * 256 + threadIdx.x;
    int k = idx & 31;
    int r = (idx >> 5) & 127;
    int g = idx >> 12;
    int m = (r - k - 32 * g) & (N - 1);
    float f = wf[m];
    unsigned h = bf16h(f);
    float hf = __uint_as_float(h << 16);
    unsigned l = bf16h(f - hf);
    th[idx] = (ushort)h;
    tl[idx] = (ushort)l;
}

__global__ void reduce_sign_kernel(const float* __restrict__ x, float* S) {
    const size_t NN = (size_t)N * N;
    float acc = 0.0f;
    for (size_t idx = (size_t)blockIdx.x * blockDim.x + threadIdx.x; idx < NN;
         idx += (size_t)gridDim.x * blockDim.x) {
        int st = (int)((idx >> 12) + (idx & (N - 1)));
        float v = x[idx];
        acc += (st & 1) ? -v : v;
    }
    #pragma unroll
    for (int off = 32; off > 0; off >>= 1) acc += __shfl_down(acc, off, 64);
    __shared__ float wsum[4];
    int lane = threadIdx.x & 63;
    int wv   = threadIdx.x >> 6;
    if (lane == 0) wsum[wv] = acc;
    __syncthreads();
    if (threadIdx.x == 0) atomicAdd(S, wsum[0] + wsum[1] + wsum[2] + wsum[3]);
}

// x -> xh/xl (row-major bf16 split) + ET even rows (x^T split) + sign-sum S
__global__ __launch_bounds__(256) void convert_x_kernel(const float* __restrict__ x,
        ushort* __restrict__ xh, ushort* __restrict__ xl,
        ushort* __restrict__ ETh, ushort* __restrict__ ETl, float* __restrict__ S) {
    __shared__ uint tile[32][33];
    __shared__ float wsum[4];
    const int bj = blockIdx.x * 32;
    const int bs = blockIdx.y * 32;
    const int tid = threadIdx.x;
    const int row = tid >> 3;         // 0..31
    const int c4  = (tid & 7) << 2;   // 0,4,..,28

    float4 v = *reinterpret_cast<const float4*>(x + (size_t)(bs + row) * N + bj + c4);
    float av[4] = {v.x, v.y, v.z, v.w};
    u16x4 h4, l4;
    float sacc = 0.0f;
    #pragma unroll
    for (int i = 0; i < 4; ++i) {
        unsigned h = bf16h(av[i]);
        float hf = __uint_as_float(h << 16);
        unsigned lo = bf16h(av[i] - hf);
        h4[i] = (unsigned short)h;
        l4[i] = (unsigned short)lo;
        tile[row][c4 + i] = (h << 16) | lo;
        sacc += (((bs + row) + (bj + c4 + i)) & 1) ? -av[i] : av[i];
    }
    size_t ro = (size_t)(bs + row) * N + bj + c4;
    *reinterpret_cast<u16x4*>(xh + ro) = h4;
    *reinterpret_cast<u16x4*>(xl + ro) = l4;

    #pragma unroll
    for (int off = 32; off > 0; off >>= 1) sacc += __shfl_down(sacc, off, 64);
    if ((tid & 63) == 0) wsum[tid >> 6] = sacc;
    __syncthreads();
    if (tid == 0) atomicAdd(S, wsum[0] + wsum[1] + wsum[2] + wsum[3]);

    // transposed write: ET[2*(bj+row)][bs + c4 + i] = x[bs+c4+i][bj+row]
    u16x4 th4, tl4;
    #pragma unroll
    for (int i = 0; i < 4; ++i) {
        uint p = tile[c4 + i][row];
        th4[i] = (unsigned short)(p >> 16);
        tl4[i] = (unsigned short)(p & 0xFFFFu);
    }
    size_t eo = (size_t)(2 * (bj + row)) * N + bs + c4;
    *reinterpret_cast<u16x4*>(ETh + eo) = th4;
    *reinterpret_cast<u16x4*>(ETl + eo) = tl4;
}

// hpass: Z[s][j] = sum_t x[s][t] w[(j-t) mod N]; writes out even rows + ET odd rows.
// XCD panel-affinity: all 32 j-tiles of one s-panel run on the same XCD.
__global__ __launch_bounds__(256) void hpass_pre(const float* __restrict__ x,
        const ushort* __restrict__ xh, const ushort* __restrict__ xl,
        const ushort* __restrict__ th, const ushort* __restrict__ tl,
        float* __restrict__ out, ushort* __restrict__ ETh, ushort* __restrict__ ETl) {
    const int n    = blockIdx.x;          // 0..1023
    const int xcd  = n & 7;               // HW dispatch: consecutive ids round-robin XCDs
    const int slot = n >> 3;              // 0..127: sequential on one XCD
    const int s0   = (xcd + 8 * (slot >> 5)) * 128;  // panel: 4 per XCD, sequential
    const int j0   = (slot & 31) * 128;              // 32 siblings share the s-panel
    const int tid = threadIdx.x;
    const int w   = tid >> 6;
    const int l   = tid & 63;
    const int lr  = l & 15;
    const int kb  = (l >> 4) * 8;
    const int wm  = (w >> 1) * 64;
    const int wn  = (w & 1) * 64;

    f32x4 acc[4][4];
    #pragma unroll
    for (int a = 0; a < 4; ++a)
        #pragma unroll
        for (int b = 0; b < 4; ++b)
            acc[a][b] = (f32x4){0.f, 0.f, 0.f, 0.f};

    #pragma unroll 2
    for (int t0 = 0; t0 < N; t0 += 32) {
        const int g = ((t0 - j0) & (N - 1)) >> 5;
        short8 bh[4], bl[4], ah[4], al[4];
        #pragma unroll
        for (int mf = 0; mf < 4; ++mf) {
            size_t ao = (size_t)(s0 + wm + mf * 16 + lr) * N + t0 + kb;
            ah[mf] = *reinterpret_cast<const short8*>(xh + ao);
            al[mf] = *reinterpret_cast<const short8*>(xl + ao);
        }
        #pragma unroll
        for (int nf = 0; nf < 4; ++nf) {
            size_t flat = ((size_t)(g * 128 + wn + nf * 16 + lr) << 5) + kb;
            bh[nf] = *reinterpret_cast<const short8*>(th + flat);
            bl[nf] = *reinterpret_cast<const short8*>(tl + flat);
        }
        // 3 independent passes: per-acc order is still hh, hl, lh (bitwise same result)
        #pragma unroll
        for (int mf = 0; mf < 4; ++mf)
            #pragma unroll
            for (int nf = 0; nf < 4; ++nf)
                acc[mf][nf] = __builtin_amdgcn_mfma_f32_16x16x32_bf16(ah[mf], bh[nf], acc[mf][nf], 0, 0, 0);
        #pragma unroll
        for (int mf = 0; mf < 4; ++mf)
            #pragma unroll
            for (int nf = 0; nf < 4; ++nf)
                acc[mf][nf] = __builtin_amdgcn_mfma_f32_16x16x32_bf16(ah[mf], bl[nf], acc[mf][nf], 0, 0, 0);
        #pragma unroll
        for (int mf = 0; mf < 4; ++mf)
            #pragma unroll
            for (int nf = 0; nf < 4; ++nf)
                acc[mf][nf] = __builtin_amdgcn_mfma_f32_16x16x32_bf16(al[mf], bh[nf], acc[mf][nf], 0, 0, 0);
    }

    const int crow = (l >> 4) * 4;
    #pragma unroll
    for (int mf = 0; mf < 4; ++mf) {
        const int sbase = s0 + wm + mf * 16 + crow;
        #pragma unroll
        for (int nf = 0; nf < 4; ++nf) {
            const int j = j0 + wn + nf * 16 + lr;
            u16x4 h4, l4;
            #pragma unroll
            for (int i = 0; i < 4; ++i) {
                float zv = acc[mf][nf][i];
                float xv = x[(size_t)(sbase + i) * N + j];
                *reinterpret_cast<float2*>(out + (size_t)(2 * (sbase + i)) * NO + (size_t)(2 * j)) =
                    make_float2(xv, zv);
                unsigned h = bf16h(zv);
                h4[i] = (unsigned short)h;
                l4[i] = (unsigned short)bf16h(zv - __uint_as_float(h << 16));
            }
            size_t eo = (size_t)(2 * j + 1) * N + sbase;
            *reinterpret_cast<u16x4*>(ETh + eo) = h4;
            *reinterpret_cast<u16x4*>(ETl + eo) = l4;
        }
    }
}

// vpass: y[2i+1][b] = sum_s w[(i-s) mod N] * E[s][b] - sign correction (odd b).
// XCD panel-affinity: all 32 i-tiles of one b-panel run on the same XCD.
__global__ __launch_bounds__(256) void vpass_pre(const ushort* __restrict__ th,
        const ushort* __restrict__ tl, const ushort* __restrict__ ETh,
        const ushort* __restrict__ ETl, const float* __restrict__ S, float* __restrict__ out) {
    const int n    = blockIdx.x;          // 0..2047
    const int xcd  = n & 7;
    const int slot = n >> 3;              // 0..255
    const int b0   = (xcd + 8 * (slot >> 5)) * 128;  // panel: 8 per XCD, sequential
    const int i0   = (slot & 31) * 128;              // 32 siblings share the b-panel
    const int tid = threadIdx.x;
    const int w   = tid >> 6;
    const int l   = tid & 63;
    const int lr  = l & 15;
    const int kb  = (l >> 4) * 8;
    const int wm  = (w >> 1) * 64;
    const int wn  = (w & 1) * 64;

    f32x4 acc[4][4];
    #pragma unroll
    for (int a = 0; a < 4; ++a)
        #pragma unroll
        for (int b = 0; b < 4; ++b)
            acc[a][b] = (f32x4){0.f, 0.f, 0.f, 0.f};

    #pragma unroll 2
    for (int s0 = 0; s0 < N; s0 += 32) {
        short8 bh[4], bl[4], ah[4], al[4];
        #pragma unroll
        for (int nf = 0; nf < 4; ++nf) {
            size_t eo = (size_t)(b0 + wn + nf * 16 + lr) * N + s0 + kb;
            bh[nf] = *reinterpret_cast<const short8*>(ETh + eo);
            bl[nf] = *reinterpret_cast<const short8*>(ETl + eo);
        }
        const int g = ((s0 - i0) & (N - 1)) >> 5;
        #pragma unroll
        for (int mf = 0; mf < 4; ++mf) {
            size_t flat = ((size_t)(g * 128 + wm + mf * 16 + lr) << 5) + kb;
            ah[mf] = *reinterpret_cast<const short8*>(th + flat);
            al[mf] = *reinterpret_cast<const short8*>(tl + flat);
        }
        #pragma unroll
        for (int mf = 0; mf < 4; ++mf)
            #pragma unroll
            for (int nf = 0; nf < 4; ++nf)
                acc[mf][nf] = __builtin_amdgcn_mfma_f32_16x16x32_bf16(ah[mf], bh[nf], acc[mf][nf], 0, 0, 0);
        #pragma unroll
        for (int mf = 0; mf < 4; ++mf)
            #pragma unroll
            for (int nf = 0; nf < 4; ++nf)
                acc[mf][nf] = __builtin_amdgcn_mfma_f32_16x16x32_bf16(ah[mf], bl[nf], acc[mf][nf], 0, 0, 0);
        #pragma unroll
        for (int mf = 0; mf < 4; ++mf)
            #pragma unroll
            for (int nf = 0; nf < 4; ++nf)
                acc[mf][nf] = __builtin_amdgcn_mfma_f32_16x16x32_bf16(al[mf], bh[nf], acc[mf][nf], 0, 0, 0);
    }

    const float Sval = S[0] * (1.0f / ((float)N * (float)N));
    const int crow = (l >> 4) * 4;
    #pragma unroll
    for (int mf = 0; mf < 4; ++mf) {
        #pragma unroll
        for (int i = 0; i < 4; ++i) {
            int irow = i0 + wm + mf * 16 + crow + i;
            #pragma unroll
            for (int nf = 0; nf < 4; ++nf) {
                int b = b0 + wn + nf * 16 + lr;
                float v = acc[mf][nf][i];
                if (b & 1) {
                    int jdx = (b - 1) >> 1;
                    v -= (((irow + jdx) & 1) ? -Sval : Sval);
                }
                out[(size_t)(2 * irow + 1) * NO + (size_t)b] = v;
            }
        }
    }
}

// ---------------- fallback (round-1) kernels: used only if workspace is small ----------------
__device__ __forceinline__ void split8(const float4& a0, const float4& a1,
                                       short8& hi, short8& lo) {
    float av[8] = {a0.x, a0.y, a0.z, a0.w, a1.x, a1.y, a1.z, a1.w};
    #pragma unroll
    for (int j = 0; j < 8; ++j) {
        unsigned h = bf16h(av[j]);
        float hf = __uint_as_float(h << 16);
        hi[j] = (short)h;
        lo[j] = (short)bf16h(av[j] - hf);
    }
}

__global__ __launch_bounds__(256) void hpass_fly(const float* __restrict__ x,
        const ushort* __restrict__ th, const ushort* __restrict__ tl,
        float* __restrict__ out) {
    const int j0 = blockIdx.x * 128;
    const int s0 = blockIdx.y * 128;
    const int tid = threadIdx.x;
    const int w = tid >> 6, l = tid & 63;
    const int lr = l & 15, kb = (l >> 4) * 8;
    const int wm = (w >> 1) * 64, wn = (w & 1) * 64;
    f32x4 acc[4][4];
    #pragma unroll
    for (int a = 0; a < 4; ++a)
        #pragma unroll
        for (int b = 0; b < 4; ++b) acc[a][b] = (f32x4){0.f, 0.f, 0.f, 0.f};
    for (int t0 = 0; t0 < N; t0 += 32) {
        const int g = ((t0 - j0) & (N - 1)) >> 5;
        short8 bh[4], bl[4];
        #pragma unroll
        for (int nf = 0; nf < 4; ++nf) {
            size_t flat = ((size_t)(g * 128 + wn + nf * 16 + lr) << 5) + kb;
            bh[nf] = *reinterpret_cast<const short8*>(th + flat);
            bl[nf] = *reinterpret_cast<const short8*>(tl + flat);
        }
        #pragma unroll
        for (int mf = 0; mf < 4; ++mf) {
            const float* ap = x + (size_t)(s0 + wm + mf * 16 + lr) * N + (t0 + kb);
            float4 a0 = *reinterpret_cast<const float4*>(ap);
            float4 a1 = *reinterpret_cast<const float4*>(ap + 4);
            short8 ah, al;
            split8(a0, a1, ah, al);
            #pragma unroll
            for (int nf = 0; nf < 4; ++nf) {
                acc[mf][nf] = __builtin_amdgcn_mfma_f32_16x16x32_bf16(ah, bh[nf], acc[mf][nf], 0, 0, 0);
                acc[mf][nf] = __builtin_amdgcn_mfma_f32_16x16x32_bf16(ah, bl[nf], acc[mf][nf], 0, 0, 0);
                acc[mf][nf] = __builtin_amdgcn_mfma_f32_16x16x32_bf16(al, bh[nf], acc[mf][nf], 0, 0, 0);
            }
        }
    }
    const int crow = (l >> 4) * 4;
    #pragma unroll
    for (int mf = 0; mf < 4; ++mf)
        #pragma unroll
        for (int i = 0; i < 4; ++i) {
            int s = s0 + wm + mf * 16 + crow + i;
            #pragma unroll
            for (int nf = 0; nf < 4; ++nf) {
                int j = j0 + wn + nf * 16 + lr;
                float xv = x[(size_t)s * N + j];
                *reinterpret_cast<float2*>(out + (size_t)(2 * s) * NO + (size_t)(2 * j)) =
                    make_float2(xv, acc[mf][nf][i]);
            }
        }
}

__global__ __launch_bounds__(256) void vpass_fly(const ushort* __restrict__ th,
        const ushort* __restrict__ tl, const float* __restrict__ S, float* out) {
    const int i0 = blockIdx.x * 128;
    const int b0 = blockIdx.y * 128;
    const int tid = threadIdx.x;
    const int w = tid >> 6, l = tid & 63;
    const int lr = l & 15, kb = (l >> 4) * 8;
    const int wm = (w >> 1) * 64, wn = (w & 1) * 64;
    f32x4 acc[4][4];
    #pragma unroll
    for (int a = 0; a < 4; ++a)
        #pragma unroll
        for (int b = 0; b < 4; ++b) acc[a][b] = (f32x4){0.f, 0.f, 0.f, 0.f};
    for (int s0 = 0; s0 < N; s0 += 32) {
        short8 bh[4], bl[4];
        #pragma unroll
        for (int nf = 0; nf < 4; ++nf) {
            int colb = b0 + wn + nf * 16 + lr;
            const float* ep = out + (size_t)(2 * (s0 + kb)) * NO + colb;
            float ev[8];
            #pragma unroll
            for (int j = 0; j < 8; ++j) ev[j] = ep[(size_t)(2 * j) * NO];
            #pragma unroll
            for (int j = 0; j < 8; ++j) {
                unsigned h = bf16h(ev[j]);
                float hf = __uint_as_float(h << 16);
                bh[nf][j] = (short)h;
                bl[nf][j] = (short)bf16h(ev[j] - hf);
            }
        }
        const int g = ((s0 - i0) & (N - 1)) >> 5;
        #pragma unroll
        for (int mf = 0; mf < 4; ++mf) {
            size_t flat = ((size_t)(g * 128 + wm + mf * 16 + lr) << 5) + kb;
            short8 ah = *reinterpret_cast<const short8*>(th + flat);
            short8 al = *reinterpret_cast<const short8*>(tl + flat);
            #pragma unroll
            for (int nf = 0; nf < 4; ++nf) {
                acc[mf][nf] = __builtin_amdgcn_mfma_f32_16x16x32_bf16(ah, bh[nf], acc[mf][nf], 0, 0, 0);
                acc[mf][nf] = __builtin_amdgcn_mfma_f32_16x16x32_bf16(ah, bl[nf], acc[mf][nf], 0, 0, 0);
                acc[mf][nf] = __builtin_amdgcn_mfma_f32_16x16x32_bf16(al, bh[nf], acc[mf][nf], 0, 0, 0);
            }
        }
    }
    const float Sval = S[0] * (1.0f / ((float)N * (float)N));
    const int crow = (l >> 4) * 4;
    #pragma unroll
    for (int mf = 0; mf < 4; ++mf)
        #pragma unroll
        for (int i = 0; i < 4; ++i) {
            int irow = i0 + wm + mf * 16 + crow + i;
            #pragma unroll
            for (int nf = 0; nf < 4; ++nf) {
                int b = b0 + wn + nf * 16 + lr;
                float v = acc[mf][nf][i];
                if (b & 1) {
                    int jdx = (b - 1) >> 1;
                    v -= (((irow + jdx) & 1) ? -Sval : Sval);
                }
                out[(size_t)(2 * irow + 1) * NO + (size_t)b] = v;
            }
        }
}

extern "C" void kernel_launch(void* const* d_in, const int* in_sizes, int n_in,
                              void* d_out, int out_size, void* d_ws, size_t ws_size,
                              hipStream_t stream) {
    const float* x = (const float*)d_in[0];
    float* out = (float*)d_out;
    char* base = (char*)d_ws;
    float* wf = (float*)base;                               // wf[0..N], S at wf[N]
    ushort* th = (ushort*)(base + 65536);
    ushort* tl = th + TBL_ELEMS;

    const size_t need = 65536 + (size_t)4 * TBL_ELEMS
                      + (size_t)4 * N * N            // xh + xl
                      + (size_t)4 * NO * N;          // ETh + ETl
    init_weights_kernel<<<(N + 255) / 256, 256, 0, stream>>>(wf);
    build_table_kernel<<<TBL_ELEMS / 256, 256, 0, stream>>>(wf, th, tl);

    if (ws_size >= need) {
        ushort* xh  = (ushort*)(base + 65536 + (size_t)4 * TBL_ELEMS);
        ushort* xl  = xh + (size_t)N * N;
        ushort* ETh = xl + (size_t)N * N;
        ushort* ETl = ETh + (size_t)NO * N;
        convert_x_kernel<<<dim3(N / 32, N / 32), 256, 0, stream>>>(x, xh, xl, ETh, ETl, wf + N);
        hpass_pre<<<1024, 256, 0, stream>>>(x, xh, xl, th, tl, out, ETh, ETl);
        vpass_pre<<<2048, 256, 0, stream>>>(th, tl, ETh, ETl, wf + N, out);
    } else {
        reduce_sign_kernel<<<1024, 256, 0, stream>>>(x, wf + N);
        hpass_fly<<<dim3(N / 128, N / 128), 256, 0, stream>>>(x, th, tl, out);
        vpass_fly<<<dim3(N / 128, NO / 128), 256, 0, stream>>>(th, tl, wf + N, out);
    }
}